// Round 8
// baseline (1961.646 us; speedup 1.0000x reference)
//
#include <hip/hip_runtime.h>
#include <stdint.h>

// Echo-state network (fp32 in, fp32 out). Round 22: R18 skeleton (proven
// 1744 us) with BK 64 -> 128: HALVE the barrier-phase count.
// R20/R21 post-mortem: tile reshapes that improved LDS-bytes/output and
// L2-bytes/output BOTH regressed => no throughput resource is binding.
// Honest arithmetic: ~3200 cy per chunk-phase vs ~600 cy countable work =>
// the step kernel is PHASE-OVERHEAD-bound (barrier straggler slack + load
// latency exposure per phase, ~650 cy x 32 phases/step). Lever: fewer,
// fatter phases. BK=128: 8 chunks x 2 barriers = 16 main barriers (was 32).
// Same K-order (kk = 0..1023 sequential) -> bit-identical numerics. LDS
// 51 KB/block, still 3 blocks/CU (153 <= 160 KB). Prefetch = 12 uint4 = 48
// VGPR held across the MFMA phase -> __launch_bounds__(256,3) pins the VGPR
// budget at 168 so the backend cannot reg-squeeze the pipeline (R19 lesson).
// Everything else verbatim R18: 768-block grid, XCD swizzle, 64x32 tile,
// hi/lo*4096 f16 split, 3 MFMAs/product, fused head partials, head_reduce.

typedef _Float16 f16;
typedef _Float16 f16x8 __attribute__((ext_vector_type(8)));
typedef float floatx4 __attribute__((ext_vector_type(4)));

#define N_TOT 256
#define T_TOT 70
#define V_TOT 64
#define B_TOT 6
#define H_TOT 1024
#define C_TOT 4
#define F_TOT (B_TOT * H_TOT)
#define G_TOT 192       // partial groups = B_TOT * 32 unit-tiles
#define LDA2 136        // f16 LDS row stride for BK=128 (272 B: bank step 4 mod 32, 2-way free)
#define LO_SCALE 4096.0f
#define LO_INV   (1.0f / 4096.0f)

union H8 { f16 h[8]; uint4 v; };

// ---------------------------------------------------------------------------
// One-time fp32 -> (hi, lo*4096) f16 split, 8 elems/thread. n % 2048 == 0.
// ---------------------------------------------------------------------------
__global__ __launch_bounds__(256)
void split_f32(const float* __restrict__ src, f16* __restrict__ hi,
               f16* __restrict__ lo, int n)
{
    const int i = (blockIdx.x * 256 + threadIdx.x) * 8;
    if (i + 8 > n) return;
    const float4 a = *(const float4*)&src[i];
    const float4 b = *(const float4*)&src[i + 4];
    const float x[8] = {a.x, a.y, a.z, a.w, b.x, b.y, b.z, b.w};
    H8 H, L;
#pragma unroll
    for (int j = 0; j < 8; ++j) {
        const f16 h = (f16)x[j];
        H.h[j] = h;
        L.h[j] = (f16)((x[j] - (float)h) * LO_SCALE);
    }
    *(uint4*)&hi[i] = H.v;
    *(uint4*)&lo[i] = L.v;
}

// ---------------------------------------------------------------------------
// Final head reduce + argmax. Block = t (70), thread = n (256).
// logits[t][n][c] = b_lin[t][c] + sum_g part[t][g][n][c]; preds = argmax.
// ---------------------------------------------------------------------------
__global__ __launch_bounds__(256)
void head_reduce(const float* __restrict__ part,
                 const float* __restrict__ b_lin,
                 float* __restrict__ logits,
                 float* __restrict__ preds)
{
    const int t = blockIdx.x;
    const int n = threadIdx.x;

    float a0 = b_lin[t * C_TOT + 0];
    float a1 = b_lin[t * C_TOT + 1];
    float a2 = b_lin[t * C_TOT + 2];
    float a3 = b_lin[t * C_TOT + 3];

    const float* p = part + (((size_t)t * G_TOT) * N_TOT + n) * C_TOT;
    for (int g = 0; g < G_TOT; ++g) {
        const float4 v = *(const float4*)&p[(size_t)g * N_TOT * C_TOT];
        a0 += v.x; a1 += v.y; a2 += v.z; a3 += v.w;
    }

    float4 o = {a0, a1, a2, a3};
    *(float4*)&logits[((size_t)t * N_TOT + n) * C_TOT] = o;

    int arg = 0;
    float best = a0;
    if (a1 > best) { best = a1; arg = 1; }
    if (a2 > best) { best = a2; arg = 2; }
    if (a3 > best) { best = a3; arg = 3; }
    preds[(size_t)t * N_TOT + n] = (float)arg;
}

// ---------------------------------------------------------------------------
// Fused step+head: S_new = tanh(S W_res^T + X_t W_in^T); partials -> part[].
// Tile 64(M=batch) x 32(I=units); grid = 6*4*32 = 768. Wave w = M-quadrant,
// 1x2 16x16x32 f16 fragments. BK=128 (8 chunks), register-prefetch one chunk
// ahead, 2 barriers/chunk. Block index XCD-swizzled (R18 map).
// ---------------------------------------------------------------------------
__global__ __launch_bounds__(256, 3)
void esn_step_fused(const f16* __restrict__ Xhi,   const f16* __restrict__ Xlo,
                    const f16* __restrict__ Whi,   const f16* __restrict__ Wlo,
                    const f16* __restrict__ Wihi,  const f16* __restrict__ Wilo,
                    const f16* __restrict__ shi_p, const f16* __restrict__ slo_p,
                    f16* __restrict__ shi_n,       f16* __restrict__ slo_n,
                    const float* __restrict__ W_lin, float* __restrict__ part,
                    int t, int first)
{
    __shared__ f16 As_hi[64 * LDA2];
    __shared__ f16 As_lo[64 * LDA2];
    __shared__ f16 Bs_hi[32 * LDA2];
    __shared__ f16 Bs_lo[32 * LDA2];

    // XCD-aware bijective swizzle (768 % 8 == 0), (b,it,mt)-major: per-XCD
    // footprint = 4 A-slices + 24 B-slices ~= 4 MB = L2-resident.
    const int p   = blockIdx.x;
    const int l   = (p & 7) * 96 + (p >> 3);
    const int mt  = l & 3;           // batch tile 0..3  (64 rows)
    const int bi  = l >> 2;          // 0..191
    const int b   = bi >> 5;         // reservoir block 0..5
    const int it  = bi & 31;         // unit tile 0..31  (32 cols)

    const int tid  = threadIdx.x;
    const int wm   = tid >> 6;       // wave = M-quadrant
    const int lane = tid & 63;
    const int l16  = lane & 15;
    const int oct  = lane >> 4;

    // staging maps (f16 elements, uint4 = 8 f16), BK=128:
    // A: 64 rows x 128 cols, 4 threads/row, 4 uint4/thread.
    // B: 32 rows x 128 cols, 8 threads/row, 2 uint4/thread.
    const int ra  = tid >> 2;         // A row 0..63
    const int caA = (tid & 3) << 5;   // A col {0,32,64,96}
    const int rb  = tid >> 3;         // B row 0..31
    const int cbB = (tid & 7) << 4;   // B col {0,16,...,112}

    floatx4 acc[2], accl[2];
#pragma unroll
    for (int j = 0; j < 2; ++j) { acc[j] = (floatx4)(0.0f); accl[j] = (floatx4)(0.0f); }

    if (!first) {
        const f16* Ah = shi_p + (size_t)(b * N_TOT + mt * 64 + ra) * H_TOT + caA;
        const f16* Al = slo_p + (size_t)(b * N_TOT + mt * 64 + ra) * H_TOT + caA;
        const f16* Bh = Whi   + (size_t)(b * H_TOT + it * 32 + rb) * H_TOT + cbB;
        const f16* Bl = Wlo   + (size_t)(b * H_TOT + it * 32 + rb) * H_TOT + cbB;

        uint4 pah0, pah1, pah2, pah3, pal0, pal1, pal2, pal3;
        uint4 pbh0, pbh1, pbl0, pbl1;
#define LOAD_CHUNK(J0)                                   \
        do {                                             \
            pah0 = *(const uint4*)&Ah[(J0) + 0];         \
            pah1 = *(const uint4*)&Ah[(J0) + 8];         \
            pah2 = *(const uint4*)&Ah[(J0) + 16];        \
            pah3 = *(const uint4*)&Ah[(J0) + 24];        \
            pal0 = *(const uint4*)&Al[(J0) + 0];         \
            pal1 = *(const uint4*)&Al[(J0) + 8];         \
            pal2 = *(const uint4*)&Al[(J0) + 16];        \
            pal3 = *(const uint4*)&Al[(J0) + 24];        \
            pbh0 = *(const uint4*)&Bh[(J0) + 0];         \
            pbh1 = *(const uint4*)&Bh[(J0) + 8];         \
            pbl0 = *(const uint4*)&Bl[(J0) + 0];         \
            pbl1 = *(const uint4*)&Bl[(J0) + 8];         \
        } while (0)

        LOAD_CHUNK(0);
        for (int kc = 0; kc < 8; ++kc) {
            if (kc) __syncthreads();   // all waves done reading previous chunk
            *(uint4*)&As_hi[ra * LDA2 + caA]      = pah0;
            *(uint4*)&As_hi[ra * LDA2 + caA + 8]  = pah1;
            *(uint4*)&As_hi[ra * LDA2 + caA + 16] = pah2;
            *(uint4*)&As_hi[ra * LDA2 + caA + 24] = pah3;
            *(uint4*)&As_lo[ra * LDA2 + caA]      = pal0;
            *(uint4*)&As_lo[ra * LDA2 + caA + 8]  = pal1;
            *(uint4*)&As_lo[ra * LDA2 + caA + 16] = pal2;
            *(uint4*)&As_lo[ra * LDA2 + caA + 24] = pal3;
            *(uint4*)&Bs_hi[rb * LDA2 + cbB]      = pbh0;
            *(uint4*)&Bs_hi[rb * LDA2 + cbB + 8]  = pbh1;
            *(uint4*)&Bs_lo[rb * LDA2 + cbB]      = pbl0;
            *(uint4*)&Bs_lo[rb * LDA2 + cbB + 8]  = pbl1;
            __syncthreads();
            if (kc < 7) LOAD_CHUNK((kc + 1) * 128);  // overlap w/ ds_read+MFMA

#pragma unroll
            for (int kk = 0; kk < 128; kk += 32) {
                const int ar = (wm * 16 + l16) * LDA2 + kk + oct * 8;
                const f16x8 ah = *(const f16x8*)&As_hi[ar];
                const f16x8 al = *(const f16x8*)&As_lo[ar];
#pragma unroll
                for (int nf = 0; nf < 2; ++nf) {
                    const int br = (nf * 16 + l16) * LDA2 + kk + oct * 8;
                    const f16x8 bh = *(const f16x8*)&Bs_hi[br];
                    const f16x8 bl = *(const f16x8*)&Bs_lo[br];
                    acc[nf]  = __builtin_amdgcn_mfma_f32_16x16x32_f16(ah, bh, acc[nf], 0, 0, 0);
                    accl[nf] = __builtin_amdgcn_mfma_f32_16x16x32_f16(ah, bl, accl[nf], 0, 0, 0);
                    accl[nf] = __builtin_amdgcn_mfma_f32_16x16x32_f16(al, bh, accl[nf], 0, 0, 0);
                }
            }
        }
#undef LOAD_CHUNK
        __syncthreads();   // chunk-7 reads done before input-term staging
    }

    // ---- input term: += X_t * W_in[b]^T  (K = V = 64) ----
    {
        const int caX = (tid & 3) << 4;   // X col {0,16,32,48}
        const int cbW = (tid & 7) << 3;   // W_in col {0,8,...,56}
        const size_t xb = ((size_t)(mt * 64 + ra) * T_TOT + t) * V_TOT + caX;
        *(uint4*)&As_hi[ra * LDA2 + caX]     = *(const uint4*)&Xhi[xb];
        *(uint4*)&As_hi[ra * LDA2 + caX + 8] = *(const uint4*)&Xhi[xb + 8];
        *(uint4*)&As_lo[ra * LDA2 + caX]     = *(const uint4*)&Xlo[xb];
        *(uint4*)&As_lo[ra * LDA2 + caX + 8] = *(const uint4*)&Xlo[xb + 8];
        const size_t wb = (size_t)(b * H_TOT + it * 32 + rb) * V_TOT + cbW;
        *(uint4*)&Bs_hi[rb * LDA2 + cbW] = *(const uint4*)&Wihi[wb];
        *(uint4*)&Bs_lo[rb * LDA2 + cbW] = *(const uint4*)&Wilo[wb];
        __syncthreads();
#pragma unroll
        for (int kk = 0; kk < 64; kk += 32) {
            const int ar = (wm * 16 + l16) * LDA2 + kk + oct * 8;
            const f16x8 ah = *(const f16x8*)&As_hi[ar];
            const f16x8 al = *(const f16x8*)&As_lo[ar];
#pragma unroll
            for (int nf = 0; nf < 2; ++nf) {
                const int br = (nf * 16 + l16) * LDA2 + kk + oct * 8;
                const f16x8 bh = *(const f16x8*)&Bs_hi[br];
                const f16x8 bl = *(const f16x8*)&Bs_lo[br];
                acc[nf]  = __builtin_amdgcn_mfma_f32_16x16x32_f16(ah, bh, acc[nf], 0, 0, 0);
                accl[nf] = __builtin_amdgcn_mfma_f32_16x16x32_f16(ah, bl, accl[nf], 0, 0, 0);
                accl[nf] = __builtin_amdgcn_mfma_f32_16x16x32_f16(al, bh, accl[nf], 0, 0, 0);
            }
        }
    }

    // ---- epilogue: tanh -> split-store state; head partial -> part[] ----
    // C/D map (16x16x32): col = lane&15, row = oct*4 + r.
    const int nbase = mt * 64;
    const int ibase = it * 32;

    const float* wl = W_lin + (size_t)t * C_TOT * F_TOT + b * H_TOT + ibase;
    float w[4][2];
#pragma unroll
    for (int c = 0; c < 4; ++c)
#pragma unroll
        for (int nf = 0; nf < 2; ++nf)
            w[c][nf] = wl[(size_t)c * F_TOT + nf * 16 + l16];

    float sval[2][4];
#pragma unroll
    for (int nf = 0; nf < 2; ++nf)
#pragma unroll
        for (int r = 0; r < 4; ++r) {
            const int m  = wm * 16 + oct * 4 + r;   // batch row within tile
            const int ii = nf * 16 + l16;           // unit col within tile
            const float s = tanhf(acc[nf][r] + accl[nf][r] * LO_INV);
            sval[nf][r] = s;
            const f16 h = (f16)s;
            const size_t oidx = (size_t)(b * N_TOT + nbase + m) * H_TOT + ibase + ii;
            shi_n[oidx] = h;
            slo_n[oidx] = (f16)((s - (float)h) * LO_SCALE);
        }

    const int g = b * 32 + it;
#pragma unroll
    for (int r = 0; r < 4; ++r) {
        float v[4];
#pragma unroll
        for (int c = 0; c < 4; ++c) {
            float x = sval[0][r] * w[c][0] + sval[1][r] * w[c][1];
            x += __shfl_xor(x, 1);
            x += __shfl_xor(x, 2);
            x += __shfl_xor(x, 4);
            x += __shfl_xor(x, 8);
            v[c] = x;
        }
        if (l16 == 0) {
            const int n = nbase + wm * 16 + oct * 4 + r;
            float4 o = {v[0], v[1], v[2], v[3]};
            *(float4*)&part[(((size_t)t * G_TOT + g) * N_TOT + n) * C_TOT] = o;
        }
    }
}

extern "C" void kernel_launch(void* const* d_in, const int* in_sizes, int n_in,
                              void* d_out, int out_size, void* d_ws, size_t ws_size,
                              hipStream_t stream) {
    const float* X     = (const float*)d_in[0]; // [256,70,64]
    const float* W_res = (const float*)d_in[1]; // [6,1024,1024]
    const float* W_in  = (const float*)d_in[2]; // [6,1024,64]
    const float* W_lin = (const float*)d_in[3]; // [70,4,6144]
    const float* b_lin = (const float*)d_in[4]; // [70,4]

    float* out    = (float*)d_out;
    float* logits = out;                                  // T*N*C fp32
    float* preds  = out + (size_t)T_TOT * N_TOT * C_TOT;  // T*N   fp32

    const size_t nWres = (size_t)B_TOT * H_TOT * H_TOT;   // 6,291,456
    const size_t nWin  = (size_t)B_TOT * H_TOT * V_TOT;   //   393,216
    const size_t nX    = (size_t)N_TOT * T_TOT * V_TOT;   // 1,146,880
    const size_t nS    = (size_t)B_TOT * N_TOT * H_TOT;   // 1,572,864

    f16* p    = (f16*)d_ws;                               // f16 arena ~43.9 MB
    f16* Whi  = p;  p += nWres;
    f16* Wlo  = p;  p += nWres;
    f16* Wihi = p;  p += nWin;
    f16* Wilo = p;  p += nWin;
    f16* Xhi  = p;  p += nX;
    f16* Xlo  = p;  p += nX;
    f16* sAh  = p;  p += nS;
    f16* sAl  = p;  p += nS;
    f16* sBh  = p;  p += nS;
    f16* sBl  = p;  p += nS;
    float* part = (float*)p;                              // +55 MB (ws ~268 MB)

    // one-time pre-splits (stream-ordered before the loop)
    split_f32<<<(int)(nWres / 2048), 256, 0, stream>>>(W_res, Whi, Wlo, (int)nWres);
    split_f32<<<(int)(nWin  / 2048), 256, 0, stream>>>(W_in, Wihi, Wilo, (int)nWin);
    split_f32<<<(int)(nX    / 2048), 256, 0, stream>>>(X, Xhi, Xlo, (int)nX);

    for (int t = 0; t < T_TOT; ++t) {
        const f16 *ph, *pl;
        f16 *nh, *nl;
        if (t & 1) { ph = sBh; pl = sBl; nh = sAh; nl = sAl; }
        else       { ph = sAh; pl = sAl; nh = sBh; nl = sBl; }
        esn_step_fused<<<B_TOT * 4 * 32, 256, 0, stream>>>(
            Xhi, Xlo, Whi, Wlo, Wihi, Wilo, ph, pl, nh, nl,
            W_lin, part, t, t == 0 ? 1 : 0);
    }
    head_reduce<<<T_TOT, 256, 0, stream>>>(part, b_lin, logits, preds);
}

// Round 9
// 1511.234 us; speedup vs baseline: 1.2980x; 1.2980x over previous
//
#include <hip/hip_runtime.h>
#include <stdint.h>

// Echo-state network (fp32 in, fp32 out). Round 23: global_load_lds staging.
// Ledger: R18 (reg-staged LDS, 2 barriers/chunk, XCD swizzle) = 1744 us is
// unbeaten; A-in-reg (x3), tile reshapes (x2), BK=128 all regressed. The one
// untried playbook lever is direct global->LDS DMA (m93->m97: +69% on the
// same reg-staged pattern). Change: staging loads become
// __builtin_amdgcn_global_load_lds width=16 into a 2-deep LDS double buffer;
// STAGE(kc+1) issued BEFORE COMPUTE(kc), ONE __syncthreads per chunk (its
// vmcnt(0) drain retires the DMA and closes the read window) -> load latency
// hidden under same-block MFMAs exactly like R14's register prefetch, but
// with zero prefetch VGPRs and zero staging ds_writes (-43% LDS-port instrs,
// -6 issue slots/thread/chunk). gload_lds writes LDS linearly (rule #21), so
// tiles are unpadded [rows][64] with XOR swizzle chunk^=(row&7) applied on
// BOTH the per-lane global source (sw = ((lane&7)^(lane>>3))<<3) and the
// ds_read address ((kk+oct*8)^((l16&7)<<3)) -> 8 bank-groups, 2-way (free).
// Same values, same MFMA order -> bit-identical numerics. Input term = chunk
// 16 of the same loop (X, W_in sources). Everything else verbatim R18:
// 768-block grid, XCD swizzle, 64x32 tile, hi/lo*4096 split, 3 MFMAs/product,
// fused head partials, head_reduce.

typedef _Float16 f16;
typedef _Float16 f16x8 __attribute__((ext_vector_type(8)));
typedef float floatx4 __attribute__((ext_vector_type(4)));

#define N_TOT 256
#define T_TOT 70
#define V_TOT 64
#define B_TOT 6
#define H_TOT 1024
#define C_TOT 4
#define F_TOT (B_TOT * H_TOT)
#define G_TOT 192       // partial groups = B_TOT * 32 unit-tiles
#define LO_SCALE 4096.0f
#define LO_INV   (1.0f / 4096.0f)

union H8 { f16 h[8]; uint4 v; };

// global->LDS DMA, 16 B per lane. LDS dest = wave-uniform base + lane*16.
#define GLOAD16(g, l)                                                        \
    __builtin_amdgcn_global_load_lds(                                        \
        (const __attribute__((address_space(1))) void*)(g),                  \
        (__attribute__((address_space(3))) void*)(l), 16, 0, 0)

// ---------------------------------------------------------------------------
// One-time fp32 -> (hi, lo*4096) f16 split, 8 elems/thread. n % 2048 == 0.
// ---------------------------------------------------------------------------
__global__ __launch_bounds__(256)
void split_f32(const float* __restrict__ src, f16* __restrict__ hi,
               f16* __restrict__ lo, int n)
{
    const int i = (blockIdx.x * 256 + threadIdx.x) * 8;
    if (i + 8 > n) return;
    const float4 a = *(const float4*)&src[i];
    const float4 b = *(const float4*)&src[i + 4];
    const float x[8] = {a.x, a.y, a.z, a.w, b.x, b.y, b.z, b.w};
    H8 H, L;
#pragma unroll
    for (int j = 0; j < 8; ++j) {
        const f16 h = (f16)x[j];
        H.h[j] = h;
        L.h[j] = (f16)((x[j] - (float)h) * LO_SCALE);
    }
    *(uint4*)&hi[i] = H.v;
    *(uint4*)&lo[i] = L.v;
}

// ---------------------------------------------------------------------------
// Final head reduce + argmax. Block = t (70), thread = n (256).
// ---------------------------------------------------------------------------
__global__ __launch_bounds__(256)
void head_reduce(const float* __restrict__ part,
                 const float* __restrict__ b_lin,
                 float* __restrict__ logits,
                 float* __restrict__ preds)
{
    const int t = blockIdx.x;
    const int n = threadIdx.x;

    float a0 = b_lin[t * C_TOT + 0];
    float a1 = b_lin[t * C_TOT + 1];
    float a2 = b_lin[t * C_TOT + 2];
    float a3 = b_lin[t * C_TOT + 3];

    const float* p = part + (((size_t)t * G_TOT) * N_TOT + n) * C_TOT;
    for (int g = 0; g < G_TOT; ++g) {
        const float4 v = *(const float4*)&p[(size_t)g * N_TOT * C_TOT];
        a0 += v.x; a1 += v.y; a2 += v.z; a3 += v.w;
    }

    float4 o = {a0, a1, a2, a3};
    *(float4*)&logits[((size_t)t * N_TOT + n) * C_TOT] = o;

    int arg = 0;
    float best = a0;
    if (a1 > best) { best = a1; arg = 1; }
    if (a2 > best) { best = a2; arg = 2; }
    if (a3 > best) { best = a3; arg = 3; }
    preds[(size_t)t * N_TOT + n] = (float)arg;
}

// ---------------------------------------------------------------------------
// Fused step+head: S_new = tanh(S W_res^T + X_t W_in^T); partials -> part[].
// Tile 64(M) x 32(I); grid = 768 (XCD-swizzled); 4 waves = M-quadrants,
// 1x2 16x16x32 f16 fragments. 17 chunks of K=64 (16 W_res + 1 W_in/X).
// Staging: global_load_lds into 2-deep LDS dbuf, 1 barrier/chunk.
// ---------------------------------------------------------------------------
__global__ __launch_bounds__(256)
void esn_step_fused(const f16* __restrict__ Xhi,   const f16* __restrict__ Xlo,
                    const f16* __restrict__ Whi,   const f16* __restrict__ Wlo,
                    const f16* __restrict__ Wihi,  const f16* __restrict__ Wilo,
                    const f16* __restrict__ shi_p, const f16* __restrict__ slo_p,
                    f16* __restrict__ shi_n,       f16* __restrict__ slo_n,
                    const float* __restrict__ W_lin, float* __restrict__ part,
                    int t, int first)
{
    __shared__ f16 As_hi[2][64 * 64];
    __shared__ f16 As_lo[2][64 * 64];
    __shared__ f16 Bs_hi[2][32 * 64];
    __shared__ f16 Bs_lo[2][32 * 64];

    // XCD-aware bijective swizzle (768 % 8 == 0), (b,it,mt)-major.
    const int p   = blockIdx.x;
    const int l   = (p & 7) * 96 + (p >> 3);
    const int mt  = l & 3;           // batch tile 0..3  (64 rows)
    const int bi  = l >> 2;          // 0..191
    const int b   = bi >> 5;         // reservoir block 0..5
    const int it  = bi & 31;         // unit tile 0..31  (32 cols)

    const int tid  = threadIdx.x;
    const int w    = tid >> 6;       // wave = M-quadrant
    const int lane = tid & 63;
    const int l16  = lane & 15;
    const int oct  = lane >> 4;
    const int r8   = lane >> 3;      // stripe row 0..7
    const int sw   = ((lane & 7) ^ r8) << 3;   // swizzled source col (f16)

    // LDS stripe bases (f16 elems) - wave-uniform
    const int dA0 = (w * 16) * 64;
    const int dA1 = (w * 16 + 8) * 64;
    const int dB  = (w * 8) * 64;

    // per-lane global row indices
    const int arow0 = mt * 64 + w * 16 + r8;   // A rows, issue 0
    const int arow1 = arow0 + 8;               // A rows, issue 1
    const int brow  = it * 32 + w * 8 + r8;    // B rows

    // source base pointers (per-lane, 16B-aligned)
    const f16* Ah0 = shi_p + (size_t)(b * N_TOT + arow0) * H_TOT + sw;
    const f16* Ah1 = shi_p + (size_t)(b * N_TOT + arow1) * H_TOT + sw;
    const f16* Al0 = slo_p + (size_t)(b * N_TOT + arow0) * H_TOT + sw;
    const f16* Al1 = slo_p + (size_t)(b * N_TOT + arow1) * H_TOT + sw;
    const f16* Bh0 = Whi   + (size_t)(b * H_TOT + brow) * H_TOT + sw;
    const f16* Bl0 = Wlo   + (size_t)(b * H_TOT + brow) * H_TOT + sw;
    const f16* Xh0 = Xhi + ((size_t)arow0 * T_TOT + t) * V_TOT + sw;
    const f16* Xh1 = Xhi + ((size_t)arow1 * T_TOT + t) * V_TOT + sw;
    const f16* Xl0 = Xlo + ((size_t)arow0 * T_TOT + t) * V_TOT + sw;
    const f16* Xl1 = Xlo + ((size_t)arow1 * T_TOT + t) * V_TOT + sw;
    const f16* Wih = Wihi + (size_t)(b * H_TOT + brow) * V_TOT + sw;
    const f16* Wil = Wilo + (size_t)(b * H_TOT + brow) * V_TOT + sw;

    // stage chunk k into buffer k&1 (k==16 -> input term X / W_in)
    auto STAGE = [&](int k) {
        const int bb = k & 1;
        if (k < 16) {
            const size_t off = (size_t)k * 64;
            GLOAD16(Ah0 + off, &As_hi[bb][dA0]);
            GLOAD16(Ah1 + off, &As_hi[bb][dA1]);
            GLOAD16(Al0 + off, &As_lo[bb][dA0]);
            GLOAD16(Al1 + off, &As_lo[bb][dA1]);
            GLOAD16(Bh0 + off, &Bs_hi[bb][dB]);
            GLOAD16(Bl0 + off, &Bs_lo[bb][dB]);
        } else {
            GLOAD16(Xh0, &As_hi[bb][dA0]);
            GLOAD16(Xh1, &As_hi[bb][dA1]);
            GLOAD16(Xl0, &As_lo[bb][dA0]);
            GLOAD16(Xl1, &As_lo[bb][dA1]);
            GLOAD16(Wih, &Bs_hi[bb][dB]);
            GLOAD16(Wil, &Bs_lo[bb][dB]);
        }
    };

    floatx4 acc[2], accl[2];
#pragma unroll
    for (int j = 0; j < 2; ++j) { acc[j] = (floatx4)(0.0f); accl[j] = (floatx4)(0.0f); }

    // swizzled ds_read addresses (f16 elems); buffer content is per-chunk but
    // addresses are chunk-invariant.
    const int xsw = (l16 & 7) << 3;
    const int aoff[2] = {
        (w * 16 + l16) * 64 + ((0 + oct * 8) ^ xsw),
        (w * 16 + l16) * 64 + ((32 + oct * 8) ^ xsw)
    };
    int boff[2][2];
#pragma unroll
    for (int nf = 0; nf < 2; ++nf) {
        boff[nf][0] = (nf * 16 + l16) * 64 + ((0 + oct * 8) ^ xsw);
        boff[nf][1] = (nf * 16 + l16) * 64 + ((32 + oct * 8) ^ xsw);
    }

    const int kc0 = first ? 16 : 0;
    STAGE(kc0);
    __syncthreads();   // vmcnt(0) drain: buffer kc0&1 ready

    for (int kc = kc0; kc <= 16; ++kc) {
        const int bb = kc & 1;
        if (kc < 16) STAGE(kc + 1);   // DMA next chunk into other buffer

#pragma unroll
        for (int half = 0; half < 2; ++half) {
            const f16x8 ah = *(const f16x8*)&As_hi[bb][aoff[half]];
            const f16x8 al = *(const f16x8*)&As_lo[bb][aoff[half]];
#pragma unroll
            for (int nf = 0; nf < 2; ++nf) {
                const f16x8 bh = *(const f16x8*)&Bs_hi[bb][boff[nf][half]];
                const f16x8 bl = *(const f16x8*)&Bs_lo[bb][boff[nf][half]];
                acc[nf]  = __builtin_amdgcn_mfma_f32_16x16x32_f16(ah, bh, acc[nf], 0, 0, 0);
                accl[nf] = __builtin_amdgcn_mfma_f32_16x16x32_f16(ah, bl, accl[nf], 0, 0, 0);
                accl[nf] = __builtin_amdgcn_mfma_f32_16x16x32_f16(al, bh, accl[nf], 0, 0, 0);
            }
        }
        if (kc < 16) __syncthreads();   // next buffer DMA'd; this buffer free
    }

    // ---- epilogue: tanh -> split-store state; head partial -> part[] ----
    // C/D map (16x16x32): col = lane&15, row = oct*4 + r.
    const int nbase = mt * 64;
    const int ibase = it * 32;

    const float* wl = W_lin + (size_t)t * C_TOT * F_TOT + b * H_TOT + ibase;
    float wv[4][2];
#pragma unroll
    for (int c = 0; c < 4; ++c)
#pragma unroll
        for (int nf = 0; nf < 2; ++nf)
            wv[c][nf] = wl[(size_t)c * F_TOT + nf * 16 + l16];

    float sval[2][4];
#pragma unroll
    for (int nf = 0; nf < 2; ++nf)
#pragma unroll
        for (int r = 0; r < 4; ++r) {
            const int m  = w * 16 + oct * 4 + r;    // batch row within tile
            const int ii = nf * 16 + l16;           // unit col within tile
            const float s = tanhf(acc[nf][r] + accl[nf][r] * LO_INV);
            sval[nf][r] = s;
            const f16 h = (f16)s;
            const size_t oidx = (size_t)(b * N_TOT + nbase + m) * H_TOT + ibase + ii;
            shi_n[oidx] = h;
            slo_n[oidx] = (f16)((s - (float)h) * LO_SCALE);
        }

    const int g = b * 32 + it;
#pragma unroll
    for (int r = 0; r < 4; ++r) {
        float v[4];
#pragma unroll
        for (int c = 0; c < 4; ++c) {
            float x = sval[0][r] * wv[c][0] + sval[1][r] * wv[c][1];
            x += __shfl_xor(x, 1);
            x += __shfl_xor(x, 2);
            x += __shfl_xor(x, 4);
            x += __shfl_xor(x, 8);
            v[c] = x;
        }
        if (l16 == 0) {
            const int n = nbase + w * 16 + oct * 4 + r;
            float4 o = {v[0], v[1], v[2], v[3]};
            *(float4*)&part[(((size_t)t * G_TOT + g) * N_TOT + n) * C_TOT] = o;
        }
    }
}

extern "C" void kernel_launch(void* const* d_in, const int* in_sizes, int n_in,
                              void* d_out, int out_size, void* d_ws, size_t ws_size,
                              hipStream_t stream) {
    const float* X     = (const float*)d_in[0]; // [256,70,64]
    const float* W_res = (const float*)d_in[1]; // [6,1024,1024]
    const float* W_in  = (const float*)d_in[2]; // [6,1024,64]
    const float* W_lin = (const float*)d_in[3]; // [70,4,6144]
    const float* b_lin = (const float*)d_in[4]; // [70,4]

    float* out    = (float*)d_out;
    float* logits = out;                                  // T*N*C fp32
    float* preds  = out + (size_t)T_TOT * N_TOT * C_TOT;  // T*N   fp32

    const size_t nWres = (size_t)B_TOT * H_TOT * H_TOT;   // 6,291,456
    const size_t nWin  = (size_t)B_TOT * H_TOT * V_TOT;   //   393,216
    const size_t nX    = (size_t)N_TOT * T_TOT * V_TOT;   // 1,146,880
    const size_t nS    = (size_t)B_TOT * N_TOT * H_TOT;   // 1,572,864

    f16* p    = (f16*)d_ws;                               // f16 arena ~43.9 MB
    f16* Whi  = p;  p += nWres;
    f16* Wlo  = p;  p += nWres;
    f16* Wihi = p;  p += nWin;
    f16* Wilo = p;  p += nWin;
    f16* Xhi  = p;  p += nX;
    f16* Xlo  = p;  p += nX;
    f16* sAh  = p;  p += nS;
    f16* sAl  = p;  p += nS;
    f16* sBh  = p;  p += nS;
    f16* sBl  = p;  p += nS;
    float* part = (float*)p;                              // +55 MB (ws ~268 MB)

    // one-time pre-splits (stream-ordered before the loop)
    split_f32<<<(int)(nWres / 2048), 256, 0, stream>>>(W_res, Whi, Wlo, (int)nWres);
    split_f32<<<(int)(nWin  / 2048), 256, 0, stream>>>(W_in, Wihi, Wilo, (int)nWin);
    split_f32<<<(int)(nX    / 2048), 256, 0, stream>>>(X, Xhi, Xlo, (int)nX);

    for (int t = 0; t < T_TOT; ++t) {
        const f16 *ph, *pl;
        f16 *nh, *nl;
        if (t & 1) { ph = sBh; pl = sBl; nh = sAh; nl = sAl; }
        else       { ph = sAh; pl = sAl; nh = sBh; nl = sBl; }
        esn_step_fused<<<B_TOT * 4 * 32, 256, 0, stream>>>(
            Xhi, Xlo, Whi, Wlo, Wihi, Wilo, ph, pl, nh, nl,
            W_lin, part, t, t == 0 ? 1 : 0);
    }
    head_reduce<<<T_TOT, 256, 0, stream>>>(part, b_lin, logits, preds);
}